// Round 1
// baseline (740.482 us; speedup 1.0000x reference)
//
#include <hip/hip_runtime.h>
#include <hip/hip_bf16.h>
#include <math.h>

// Problem constants (fixed by the reference)
#define E_N 800000
#define C_N 64
#define H_N 4
#define D_N 16
#define NODES 50000

typedef __bf16 bf16x8 __attribute__((ext_vector_type(8)));
typedef float f32x4 __attribute__((ext_vector_type(4)));

__device__ __forceinline__ unsigned short f2bf_rne(float f) {
    unsigned int u = __float_as_uint(f);
    u += 0x7fffu + ((u >> 16) & 1u);
    return (unsigned short)(u >> 16);
}

union BfPack { bf16x8 v; unsigned short s[8]; };

// Load 8 consecutive fp32 and round-to-nearest-even into a bf16x8 A-fragment slice.
__device__ __forceinline__ bf16x8 load_row_bf16(const float* __restrict__ p) {
    const float4* p4 = (const float4*)p;
    float4 a = p4[0], b = p4[1];
    BfPack u;
    u.s[0] = f2bf_rne(a.x); u.s[1] = f2bf_rne(a.y);
    u.s[2] = f2bf_rne(a.z); u.s[3] = f2bf_rne(a.w);
    u.s[4] = f2bf_rne(b.x); u.s[5] = f2bf_rne(b.y);
    u.s[6] = f2bf_rne(b.z); u.s[7] = f2bf_rne(b.w);
    return u.v;
}

// ---------------------------------------------------------------------------
// Kernel 1: transpose W (fp32 [c][o]) -> Wt (bf16 [o][c]) for B-fragment loads.
// wt holds 3 matrices: Wq^T, Wk^T, Wv^T, each 64*64 bf16.
__global__ void wt_kernel(const float* __restrict__ Wq,
                          const float* __restrict__ Wk,
                          const float* __restrict__ Wv,
                          unsigned short* __restrict__ wt) {
    int t = threadIdx.x;  // 256 threads, 1 block
    for (int w = 0; w < 3; ++w) {
        const float* W = (w == 0) ? Wq : (w == 1) ? Wk : Wv;
        for (int i = t; i < 4096; i += 256) {
            int o = i >> 6, c = i & 63;
            wt[w * 4096 + i] = f2bf_rne(W[c * 64 + o]);
        }
    }
}

// ---------------------------------------------------------------------------
// Kernel 2: q/k projection via MFMA + per-(edge,head) score + atomicMax into smax.
// Wave handles 16 edges. C/D layout: col=lane&15, row=(lane>>4)*4+reg.
// A layout: m=lane&15, k=(lane>>4)*8+j.  B layout: n=lane&15, k=(lane>>4)*8+j.
__global__ __launch_bounds__(256) void score_kernel(
    const float* __restrict__ query, const float* __restrict__ key,
    const float* __restrict__ bq, const float* __restrict__ bk,
    const int* __restrict__ index,
    const unsigned short* __restrict__ wt,
    float* __restrict__ score, int* __restrict__ smax) {
    int lane = threadIdx.x & 63;
    int wid  = threadIdx.x >> 6;
    int e0   = blockIdx.x * 64 + wid * 16;
    int m    = lane & 15, quad = lane >> 4;

    const float* qrow = query + (size_t)(e0 + m) * 64 + quad * 8;
    const float* krow = key   + (size_t)(e0 + m) * 64 + quad * 8;
    bf16x8 aq0 = load_row_bf16(qrow);
    bf16x8 aq1 = load_row_bf16(qrow + 32);
    bf16x8 ak0 = load_row_bf16(krow);
    bf16x8 ak1 = load_row_bf16(krow + 32);

    const bf16x8* wq8 = (const bf16x8*)(wt);
    const bf16x8* wk8 = (const bf16x8*)(wt + 4096);

    for (int h = 0; h < H_N; ++h) {
        // B frag index: ((h*16+m)*64 + s*32 + quad*8) / 8
        int bi0 = (h * 16 + m) * 8 + quad;      // s=0
        int bi1 = bi0 + 4;                      // s=1
        f32x4 cq = {0.f, 0.f, 0.f, 0.f}, ck = {0.f, 0.f, 0.f, 0.f};
        cq = __builtin_amdgcn_mfma_f32_16x16x32_bf16(aq0, wq8[bi0], cq, 0, 0, 0);
        cq = __builtin_amdgcn_mfma_f32_16x16x32_bf16(aq1, wq8[bi1], cq, 0, 0, 0);
        ck = __builtin_amdgcn_mfma_f32_16x16x32_bf16(ak0, wk8[bi0], ck, 0, 0, 0);
        ck = __builtin_amdgcn_mfma_f32_16x16x32_bf16(ak1, wk8[bi1], ck, 0, 0, 0);
        float bqv = bq[h * 16 + m], bkv = bk[h * 16 + m];
        float p[4];
        #pragma unroll
        for (int r = 0; r < 4; ++r) p[r] = (cq[r] + bqv) * (ck[r] + bkv);
        // sum over the 16 head-columns: butterfly across lane bits 0..3
        #pragma unroll
        for (int r = 0; r < 4; ++r) {
            p[r] += __shfl_xor(p[r], 1, 64);
            p[r] += __shfl_xor(p[r], 2, 64);
            p[r] += __shfl_xor(p[r], 4, 64);
            p[r] += __shfl_xor(p[r], 8, 64);
        }
        if (m == 0) {
            #pragma unroll
            for (int r = 0; r < 4; ++r) {
                int e = e0 + quad * 4 + r;
                float s = p[r] * 0.25f;  // / sqrt(16)
                score[e * 4 + h] = s;
                if (s > 0.f) {
                    int n = index[e];
                    atomicMax(smax + n * 4 + h, __float_as_int(s));
                }
            }
        }
    }
}

// ---------------------------------------------------------------------------
// Kernel 3: denom[n,h] = exp(-smax[n,h])   (the margin term; empty segments -> 1)
__global__ void denom_init_kernel(const int* __restrict__ smax,
                                  float* __restrict__ denom) {
    int i = blockIdx.x * 256 + threadIdx.x;
    if (i < NODES * H_N) denom[i] = __expf(-__int_as_float(smax[i]));
}

// ---------------------------------------------------------------------------
// Kernel 4: denom[n,h] += sum_e exp(score[e,h] - smax[n,h])
__global__ __launch_bounds__(256) void expsum_kernel(
    const float* __restrict__ score, const int* __restrict__ index,
    const int* __restrict__ smax, float* __restrict__ denom) {
    int t = blockIdx.x * 256 + threadIdx.x;  // over E*H
    int e = t >> 2, h = t & 3;
    int n = index[e];
    float sm = __int_as_float(smax[n * 4 + h]);
    float ex = __expf(score[t] - sm);
    atomicAdd(denom + n * 4 + h, ex);
}

// ---------------------------------------------------------------------------
// Kernel 5: v projection via MFMA, scale by attn, store out.
__global__ __launch_bounds__(256) void out_kernel(
    const float* __restrict__ value, const float* __restrict__ bv,
    const int* __restrict__ index, const unsigned short* __restrict__ wt,
    const float* __restrict__ score, const int* __restrict__ smax_i,
    const float* __restrict__ denom, float* __restrict__ out) {
    int lane = threadIdx.x & 63;
    int wid  = threadIdx.x >> 6;
    int e0   = blockIdx.x * 64 + wid * 16;
    int m    = lane & 15, quad = lane >> 4;

    // one lane per (edge, head): lane l -> edge e0+(l>>2), head l&3
    int ee = e0 + (lane >> 2), hh = lane & 3;
    int n  = index[ee];
    float sm = __int_as_float(smax_i[n * 4 + hh]);
    float attn = __expf(score[ee * 4 + hh] - sm) / denom[n * 4 + hh];

    const float* vrow = value + (size_t)(e0 + m) * 64 + quad * 8;
    bf16x8 av0 = load_row_bf16(vrow);
    bf16x8 av1 = load_row_bf16(vrow + 32);
    const bf16x8* wv8 = (const bf16x8*)(wt + 8192);

    for (int h = 0; h < H_N; ++h) {
        int bi0 = (h * 16 + m) * 8 + quad;
        f32x4 cv = {0.f, 0.f, 0.f, 0.f};
        cv = __builtin_amdgcn_mfma_f32_16x16x32_bf16(av0, wv8[bi0], cv, 0, 0, 0);
        cv = __builtin_amdgcn_mfma_f32_16x16x32_bf16(av1, wv8[bi0 + 4], cv, 0, 0, 0);
        float bvv = bv[h * 16 + m];
        #pragma unroll
        for (int r = 0; r < 4; ++r) {
            int row = quad * 4 + r;
            float a = __shfl(attn, (row << 2) | h, 64);
            out[(size_t)(e0 + row) * 64 + h * 16 + m] = (cv[r] + bvv) * a;
        }
    }
}

// ---------------------------------------------------------------------------
extern "C" void kernel_launch(void* const* d_in, const int* in_sizes, int n_in,
                              void* d_out, int out_size, void* d_ws, size_t ws_size,
                              hipStream_t stream) {
    const float* query = (const float*)d_in[0];
    const float* key   = (const float*)d_in[1];
    const float* value = (const float*)d_in[2];
    const float* Wq    = (const float*)d_in[3];
    const float* bq    = (const float*)d_in[4];
    const float* Wk    = (const float*)d_in[5];
    const float* bk    = (const float*)d_in[6];
    const float* Wv    = (const float*)d_in[7];
    const float* bv    = (const float*)d_in[8];
    const int*   index = (const int*)d_in[9];

    // workspace layout
    char* ws = (char*)d_ws;
    unsigned short* wt = (unsigned short*)ws;                       // 24576 B
    float* score = (float*)(ws + 32768);                            // E*4*4 = 12.8 MB
    int*   smax  = (int*)(ws + 32768 + (size_t)E_N * 16);           // N*4*4
    float* denom = (float*)(ws + 32768 + (size_t)E_N * 16 + (size_t)NODES * 16);

    hipMemsetAsync(smax, 0, (size_t)NODES * 16, stream);            // smax = 0.0f
    wt_kernel<<<1, 256, 0, stream>>>(Wq, Wk, Wv, wt);
    score_kernel<<<E_N / 64, 256, 0, stream>>>(query, key, bq, bk, index, wt,
                                               score, smax);
    denom_init_kernel<<<(NODES * H_N + 255) / 256, 256, 0, stream>>>(smax, denom);
    expsum_kernel<<<(E_N * H_N) / 256, 256, 0, stream>>>(score, index, smax, denom);
    out_kernel<<<E_N / 64, 256, 0, stream>>>(value, bv, index, wt, score, smax,
                                             denom, (float*)d_out);
}

// Round 2
// 669.945 us; speedup vs baseline: 1.1053x; 1.1053x over previous
//
#include <hip/hip_runtime.h>
#include <hip/hip_bf16.h>
#include <math.h>

// Problem constants (fixed by the reference)
#define E_N 800000
#define C_N 64
#define H_N 4
#define D_N 16
#define NODES 50000

typedef __bf16 bf16x8 __attribute__((ext_vector_type(8)));
typedef float f32x4 __attribute__((ext_vector_type(4)));

__device__ __forceinline__ unsigned short f2bf_rne(float f) {
    unsigned int u = __float_as_uint(f);
    u += 0x7fffu + ((u >> 16) & 1u);
    return (unsigned short)(u >> 16);
}

union BfPack { bf16x8 v; unsigned short s[8]; };

// Load 8 consecutive fp32 and round-to-nearest-even into a bf16x8 A-fragment slice.
__device__ __forceinline__ bf16x8 load_row_bf16(const float* __restrict__ p) {
    const float4* p4 = (const float4*)p;
    float4 a = p4[0], b = p4[1];
    BfPack u;
    u.s[0] = f2bf_rne(a.x); u.s[1] = f2bf_rne(a.y);
    u.s[2] = f2bf_rne(a.z); u.s[3] = f2bf_rne(a.w);
    u.s[4] = f2bf_rne(b.x); u.s[5] = f2bf_rne(b.y);
    u.s[6] = f2bf_rne(b.z); u.s[7] = f2bf_rne(b.w);
    return u.v;
}

// ---------------------------------------------------------------------------
// Kernel 1: transpose W (fp32 [c][o]) -> Wt (bf16 [o][c]) for B-fragment loads.
__global__ void wt_kernel(const float* __restrict__ Wq,
                          const float* __restrict__ Wk,
                          const float* __restrict__ Wv,
                          unsigned short* __restrict__ wt) {
    int t = threadIdx.x;  // 256 threads, 1 block
    for (int w = 0; w < 3; ++w) {
        const float* W = (w == 0) ? Wq : (w == 1) ? Wk : Wv;
        for (int i = t; i < 4096; i += 256) {
            int o = i >> 6, c = i & 63;
            wt[w * 4096 + i] = f2bf_rne(W[c * 64 + o]);
        }
    }
}

// ---------------------------------------------------------------------------
// Kernel 2: q/k projection (MFMA) -> per-(edge,head) score.
// Wave = 16 edges. After the 16-col butterfly, lane l owns (e=l>>2, h=l&3):
// coalesced score store + segmented max-scan + tail-only atomicMax.
__global__ __launch_bounds__(256) void score_kernel(
    const float* __restrict__ query, const float* __restrict__ key,
    const float* __restrict__ bq, const float* __restrict__ bk,
    const int* __restrict__ index,
    const unsigned short* __restrict__ wt,
    float* __restrict__ score, int* __restrict__ smax) {
    int lane = threadIdx.x & 63;
    int wid  = threadIdx.x >> 6;
    int e0   = blockIdx.x * 64 + wid * 16;
    int m    = lane & 15, quad = lane >> 4;

    const float* qrow = query + (size_t)(e0 + m) * 64 + quad * 8;
    const float* krow = key   + (size_t)(e0 + m) * 64 + quad * 8;
    bf16x8 aq0 = load_row_bf16(qrow);
    bf16x8 aq1 = load_row_bf16(qrow + 32);
    bf16x8 ak0 = load_row_bf16(krow);
    bf16x8 ak1 = load_row_bf16(krow + 32);

    const bf16x8* wq8 = (const bf16x8*)(wt);
    const bf16x8* wk8 = (const bf16x8*)(wt + 4096);

    int erel = lane >> 2;   // edge within wave, 0..15
    int hl   = lane & 3;    // head owned by this lane
    int rw   = erel & 3;    // which acc reg holds my edge's score
    float s_mine = 0.f;

    #pragma unroll
    for (int h = 0; h < H_N; ++h) {
        int bi0 = (h * 16 + m) * 8 + quad;      // s=0
        int bi1 = bi0 + 4;                      // s=1
        f32x4 cq = {0.f, 0.f, 0.f, 0.f}, ck = {0.f, 0.f, 0.f, 0.f};
        cq = __builtin_amdgcn_mfma_f32_16x16x32_bf16(aq0, wq8[bi0], cq, 0, 0, 0);
        cq = __builtin_amdgcn_mfma_f32_16x16x32_bf16(aq1, wq8[bi1], cq, 0, 0, 0);
        ck = __builtin_amdgcn_mfma_f32_16x16x32_bf16(ak0, wk8[bi0], ck, 0, 0, 0);
        ck = __builtin_amdgcn_mfma_f32_16x16x32_bf16(ak1, wk8[bi1], ck, 0, 0, 0);
        float bqv = bq[h * 16 + m], bkv = bk[h * 16 + m];
        float p[4];
        #pragma unroll
        for (int r = 0; r < 4; ++r) p[r] = (cq[r] + bqv) * (ck[r] + bkv);
        // sum over the 16 head-cols: butterfly across lane bits 0..3 (all lanes get it)
        #pragma unroll
        for (int r = 0; r < 4; ++r) {
            p[r] += __shfl_xor(p[r], 1, 64);
            p[r] += __shfl_xor(p[r], 2, 64);
            p[r] += __shfl_xor(p[r], 4, 64);
            p[r] += __shfl_xor(p[r], 8, 64);
        }
        float pw = (rw == 0) ? p[0] : (rw == 1) ? p[1] : (rw == 2) ? p[2] : p[3];
        if (h == hl) s_mine = pw * 0.25f;   // / sqrt(D=16)
    }

    // coalesced 256B store: score[e,h] with lane = (e-e0)*4 + h
    score[(size_t)e0 * 4 + lane] = s_mine;

    // segmented inclusive max-scan over edges (index sorted -> contiguous runs)
    int e = e0 + erel;
    int n = index[e];
    float s = s_mine;
    #pragma unroll
    for (int d = 4; d <= 32; d <<= 1) {   // edge distance 1,2,4,8
        float up = __shfl_up(s, d, 64);
        int  nup = __shfl_up(n, d, 64);
        if (lane >= d && nup == n) s = fmaxf(s, up);
    }
    bool tail = (erel == 15) || (index[e + 1] != n);
    if (tail && s > 0.f)
        atomicMax(smax + n * 4 + hl, __float_as_int(s));
}

// ---------------------------------------------------------------------------
// Kernel 3: denom[n,h] += segment-sum of exp(score - smax), wave-aggregated.
__global__ __launch_bounds__(256) void expsum_kernel(
    const float* __restrict__ score, const int* __restrict__ index,
    const int* __restrict__ smax, float* __restrict__ denom) {
    int lane = threadIdx.x & 63;
    int wid  = threadIdx.x >> 6;
    int e0   = blockIdx.x * 64 + wid * 16;
    int erel = lane >> 2, h = lane & 3;
    int e = e0 + erel;
    int n = index[e];
    float sm = __int_as_float(smax[n * 4 + h]);
    float s = __expf(score[(size_t)e0 * 4 + lane] - sm);
    #pragma unroll
    for (int d = 4; d <= 32; d <<= 1) {
        float up = __shfl_up(s, d, 64);
        int  nup = __shfl_up(n, d, 64);
        if (lane >= d && nup == n) s += up;
    }
    bool tail = (erel == 15) || (index[e + 1] != n);
    if (tail)
        atomicAdd(denom + n * 4 + h, s);
}

// ---------------------------------------------------------------------------
// Kernel 4: nd[n,h] = {smax, 1/(denom + exp(-smax))}
__global__ void finalize_kernel(const int* __restrict__ smax,
                                const float* __restrict__ denom,
                                float2* __restrict__ nd) {
    int i = blockIdx.x * 256 + threadIdx.x;
    if (i < NODES * H_N) {
        float sm = __int_as_float(smax[i]);
        float d  = denom[i] + __expf(-sm);
        nd[i] = make_float2(sm, 1.f / d);
    }
}

// ---------------------------------------------------------------------------
// Kernel 5: v projection via MFMA, scale by attn, store out.
__global__ __launch_bounds__(256) void out_kernel(
    const float* __restrict__ value, const float* __restrict__ bv,
    const int* __restrict__ index, const unsigned short* __restrict__ wt,
    const float* __restrict__ score, const float2* __restrict__ nd,
    float* __restrict__ out) {
    int lane = threadIdx.x & 63;
    int wid  = threadIdx.x >> 6;
    int e0   = blockIdx.x * 64 + wid * 16;
    int m    = lane & 15, quad = lane >> 4;

    // lane l owns (edge e0+(l>>2), head l&3)
    int erel = lane >> 2, hl = lane & 3;
    int n  = index[e0 + erel];
    float2 t = nd[n * 4 + hl];
    float attn = __expf(score[(size_t)e0 * 4 + lane] - t.x) * t.y;

    const float* vrow = value + (size_t)(e0 + m) * 64 + quad * 8;
    bf16x8 av0 = load_row_bf16(vrow);
    bf16x8 av1 = load_row_bf16(vrow + 32);
    const bf16x8* wv8 = (const bf16x8*)(wt + 8192);

    #pragma unroll
    for (int h = 0; h < H_N; ++h) {
        int bi0 = (h * 16 + m) * 8 + quad;
        f32x4 cv = {0.f, 0.f, 0.f, 0.f};
        cv = __builtin_amdgcn_mfma_f32_16x16x32_bf16(av0, wv8[bi0], cv, 0, 0, 0);
        cv = __builtin_amdgcn_mfma_f32_16x16x32_bf16(av1, wv8[bi0 + 4], cv, 0, 0, 0);
        float bvv = bv[h * 16 + m];
        #pragma unroll
        for (int r = 0; r < 4; ++r) {
            int row = quad * 4 + r;
            float a = __shfl(attn, (row << 2) | h, 64);
            out[(size_t)(e0 + row) * 64 + h * 16 + m] = (cv[r] + bvv) * a;
        }
    }
}

// ---------------------------------------------------------------------------
extern "C" void kernel_launch(void* const* d_in, const int* in_sizes, int n_in,
                              void* d_out, int out_size, void* d_ws, size_t ws_size,
                              hipStream_t stream) {
    const float* query = (const float*)d_in[0];
    const float* key   = (const float*)d_in[1];
    const float* value = (const float*)d_in[2];
    const float* Wq    = (const float*)d_in[3];
    const float* bq    = (const float*)d_in[4];
    const float* Wk    = (const float*)d_in[5];
    const float* bk    = (const float*)d_in[6];
    const float* Wv    = (const float*)d_in[7];
    const float* bv    = (const float*)d_in[8];
    const int*   index = (const int*)d_in[9];

    // workspace layout
    char* ws = (char*)d_ws;
    unsigned short* wt = (unsigned short*)ws;                         // 24576 B (pad 32768)
    float* score = (float*)(ws + 32768);                              // E*4*4 = 12.8 MB
    char*  p2    = ws + 32768 + (size_t)E_N * 16;
    int*   smax  = (int*)p2;                                          // N*4*4
    float* denom = (float*)(p2 + (size_t)NODES * 16);                 // N*4*4
    float2* nd   = (float2*)(p2 + 2 * (size_t)NODES * 16);            // N*4*8

    // smax = 0.0f (clamp floor), denom = 0.0f — contiguous, one memset
    hipMemsetAsync(smax, 0, 2 * (size_t)NODES * 16, stream);
    wt_kernel<<<1, 256, 0, stream>>>(Wq, Wk, Wv, wt);
    score_kernel<<<E_N / 64, 256, 0, stream>>>(query, key, bq, bk, index, wt,
                                               score, smax);
    expsum_kernel<<<E_N / 64, 256, 0, stream>>>(score, index, smax, denom);
    finalize_kernel<<<(NODES * H_N + 255) / 256, 256, 0, stream>>>(smax, denom, nd);
    out_kernel<<<E_N / 64, 256, 0, stream>>>(value, bv, index, wt, score, nd,
                                             (float*)d_out);
}